// Round 8
// baseline (453.677 us; speedup 1.0000x reference)
//
#include <hip/hip_runtime.h>
#include <math.h>

#define NPTS 1024
#define CAND 224   // 7*32
#define KEFF 64
#define BATCH 2
#define NEGV -1e30f
#define NBLK 512
#define BAR_STRIDE 16   // 64B per arrival flag (no false sharing)

// R8 = R7 with Dp/sq ELIMINATED: gram+select fused in-block (registers + LDS).
// R7 post-mortem: bound by sc1 write-through path. Logical sc-written bytes ~47MB
// x ~4 (8B stores -> 32B sectors) ~= 188MB = WRITE_SIZE; partial-line fills explain
// FETCH. Dp alone is ~33MB logical (~130MB amplified) + 33MB read. Fix: one fused
// job per (i, b, query-octet) computes full-Cin gram in regs (7 cands x 8 queries
// per thread), per-column sums-of-squares in LDS, u64 keys + rank-count in-block.
// Dp, sq buffers and the select stage + 1 barrier/layer are gone (12 -> 8 barriers).
// Numerics replicated exactly: per-chunk partials added in chunk order (= old
// Dp-partial sum order); sq as same-order fmaf chain => bit-identical selection.

#define AG __HIP_MEMORY_SCOPE_AGENT
__device__ __forceinline__ float cld(const float* p) {
    return __hip_atomic_load((float*)p, __ATOMIC_RELAXED, AG);
}
__device__ __forceinline__ void cst(float* p, float v) {
    __hip_atomic_store(p, v, __ATOMIC_RELAXED, AG);
}
__device__ __forceinline__ void csti(int* p, int v) {
    __hip_atomic_store(p, v, __ATOMIC_RELAXED, AG);
}
__device__ __forceinline__ void cst2(float* p, float2 v) {
    union { float2 f; unsigned long long u; } c; c.f = v;
    __hip_atomic_store((unsigned long long*)p, c.u, __ATOMIC_RELAXED, AG);
}

// ================================================================ weight prep (+ barrier init)
__global__ __launch_bounds__(256) void kprep(const float* __restrict__ w0, const float* __restrict__ w1,
                                             const float* __restrict__ w2, const float* __restrict__ w3,
                                             const float* __restrict__ wl, float* __restrict__ wt,
                                             unsigned* __restrict__ bar) {
    __shared__ float tA[32][33];
    __shared__ float tB[32][33];
    int id = blockIdx.x;
    int t = threadIdx.x;
    for (int i = id * 256 + t; i < NBLK * BAR_STRIDE + BAR_STRIDE; i += 204 * 256)
        bar[i] = 0u;
    int row = t >> 5, col = t & 31;
    const float* W = w0; int Cin = 256, Co = 128; float* WtA = wt; float* WtB = wt + 32768;
    int tc = 0, to = 0; bool isWL = false;
    if (id < 32)      { int r = id;      tc = r >> 2; to = r & 3; }
    else if (id < 48) { W = w1; Cin = 128; Co = 128; WtA = wt + 65536;  WtB = wt + 81920;  int r = id - 32; tc = r >> 2; to = r & 3; }
    else if (id < 56) { W = w2; Cin = 128; Co = 64;  WtA = wt + 98304;  WtB = wt + 106496; int r = id - 48; tc = r >> 1; to = r & 1; }
    else if (id < 60) { W = w3; Cin = 64;  Co = 64;  WtA = wt + 114688; WtB = wt + 118784; int r = id - 56; tc = r >> 1; to = r & 1; }
    else { isWL = true; int r = id - 60; tc = r / 12; to = r % 12; }
    if (!isWL) {
#pragma unroll
        for (int r = 0; r < 4; ++r) {
            int o = to * 32 + row + r * 8;
            int c = tc * 32 + col;
            float va = W[(size_t)o * 2 * Cin + c];
            tA[row + r * 8][col] = va;
            tB[row + r * 8][col] = W[(size_t)o * 2 * Cin + Cin + c] - va;
        }
        __syncthreads();
#pragma unroll
        for (int r = 0; r < 4; ++r) {
            int c = tc * 32 + row + r * 8;
            int o = to * 32 + col;
            WtA[(size_t)c * Co + o] = tA[col][row + r * 8];
            WtB[(size_t)c * Co + o] = tB[col][row + r * 8];
        }
    } else {
        float* wlT = wt + 122880;
#pragma unroll
        for (int r = 0; r < 4; ++r) {
            int o = to * 32 + row + r * 8;
            int c = tc * 32 + col;
            tA[row + r * 8][col] = wl[(size_t)o * 384 + c];
        }
        __syncthreads();
#pragma unroll
        for (int r = 0; r < 4; ++r) {
            int c = tc * 32 + row + r * 8;
            int o = to * 32 + col;
            wlT[(size_t)c * 384 + o] = tA[col][row + r * 8];
        }
    }
}

// ================================================================ grid barrier (fence-free: coherent flags only)
__device__ __forceinline__ void gbar(unsigned* bar, unsigned ep) {
    __syncthreads();   // hw-drains vmcnt(0): all sc1 data stores ack'd at the coherent point
    const int t = threadIdx.x;
    const int bid = blockIdx.x;
    unsigned* rel = bar + (size_t)NBLK * BAR_STRIDE;
    if (bid == 0) {
        if (t == 0)
            __hip_atomic_store(&bar[0], ep, __ATOMIC_RELAXED, AG);
        for (int s = t; s < NBLK; s += 256) {
            while (__hip_atomic_load(&bar[(size_t)s * BAR_STRIDE], __ATOMIC_RELAXED, AG) < ep)
                __builtin_amdgcn_s_sleep(1);
        }
        __syncthreads();
        if (t == 0)
            __hip_atomic_store(rel, ep, __ATOMIC_RELAXED, AG);
    } else {
        if (t == 0) {
            __hip_atomic_store(&bar[(size_t)bid * BAR_STRIDE], ep, __ATOMIC_RELAXED, AG);
            while (__hip_atomic_load(rel, __ATOMIC_RELAXED, AG) < ep)
                __builtin_amdgcn_s_sleep(1);
        }
    }
    __syncthreads();
}

// ================================================================ the fused persistent kernel
struct MP {
    const float* x;
    const float* g0; const float* g1; const float* g2; const float* g3;
    const float* be0; const float* be1; const float* be2; const float* be3;
    float* xconM; float* A; float* Bv; float* part; float* wt;
    int* idx; unsigned* bar; float* out;
};

__global__ __launch_bounds__(256, 3) void kmega(MP P) {
    // union layout: roleA/final <=7168 floats; fused sel: Xc[0..7168) keys@7168 (3584 f = 1792 u64) sq@10752
    __shared__ __align__(16) float smem[10976];
    __shared__ float shsc[384];
    __shared__ float shsh[384];
    const int t = threadIdx.x;
    const int bid = blockIdx.x;
    unsigned ep = 0;

#pragma unroll 1
    for (int l = 0; l < 4; ++l) {
        const int Cin   = (l == 0) ? 256 : (l == 3) ? 64 : 128;
        const int Co    = (l < 2) ? 128 : 64;
        const int chOut = (l == 0) ? 0 : (l == 1) ? 128 : (l == 2) ? 256 : 320;
        const float* xin = (l == 0) ? P.x : P.xconM + (size_t)(l - 1) * 131072;
        const int bstride = (l == 0) ? 262144 : 393216;
        const float* WtA = P.wt + ((l == 0) ? 0 : (l == 1) ? 65536 : (l == 2) ? 98304 : 114688);
        const float* WtB = P.wt + ((l == 0) ? 32768 : (l == 1) ? 81920 : (l == 2) ? 106496 : 118784);
        int* idxl = P.idx + (size_t)l * 131072;          // versioned per layer (write-once -> cached reads)

        // BN scale/shift for this layer's input (prev layer's 4 partials per channel) — cached reads
        if (l > 0 && t < Cin) {
            const float* pp = P.part + (size_t)(l - 1) * 1024;
            const float* gPr = (l == 1) ? P.g0  : (l == 2) ? P.g1  : P.g2;
            const float* bPr = (l == 1) ? P.be0 : (l == 2) ? P.be1 : P.be2;
            float s  = pp[4 * t]     + pp[4 * t + 2]     + pp[4 * (Cin + t)]     + pp[4 * (Cin + t) + 2];
            float s2 = pp[4 * t + 1] + pp[4 * t + 3]     + pp[4 * (Cin + t) + 1] + pp[4 * (Cin + t) + 3];
            const float invc = 1.f / 131072.f;
            float mu = s * invc;
            float var = s2 * invc - mu * mu;
            float rs = rsqrtf(var + 1e-5f);
            float sc = gPr[t] * rs;
            shsc[t] = sc;
            shsh[t] = bPr[t] - mu * sc;
        }
        __syncthreads();

        // ================ stage 1: roleA (A/Bv tiles) + fused gram+select (idx) ================
        const int nOT = Co >> 6;
        const int notLg = nOT - 1;          // 2->1, 1->0
        const int nABx = 32 * nOT * BATCH;
        const int nJobs = nABx + 256;       // 256 fused-select jobs: (i:32) x (qo:4) x (b:2)
#pragma unroll 1
        for (int job = bid; job < nJobs; job += NBLK) {
            if (job < nABx) {
                // ---------------- role A: 32n x 64o tile; thread = 4o x 2n
                int nt = job & 31; int rest = job >> 5;
                int ot = rest & (nOT - 1); int b = rest >> notLg;
                int tn2 = (t & 15) * 2, to4 = (t >> 4) * 4;
                int n0 = nt * 32, o0 = ot * 64;
                const float* xb = xin + (size_t)b * bstride + n0;
                float* Xs = smem; float* Wta = smem + 1024; float* Wtb = smem + 3200;
                float2 a2[4], b2[4];
#pragma unroll
                for (int q = 0; q < 4; ++q) { a2[q] = make_float2(0.f, 0.f); b2[q] = make_float2(0.f, 0.f); }
                int xcc0 = t >> 5, xnn = t & 31;
                int wcc0 = t >> 6, woo = t & 63;
                for (int c0 = 0; c0 < Cin; c0 += 32) {
                    float rx[4], ra[8], rb[8];
#pragma unroll
                    for (int k = 0; k < 4; ++k)
                        rx[k] = xb[(size_t)(c0 + xcc0 + k * 8) * NPTS + xnn];   // cached
#pragma unroll
                    for (int k = 0; k < 8; ++k) {
                        ra[k] = WtA[(size_t)(c0 + wcc0 + k * 4) * Co + o0 + woo];
                        rb[k] = WtB[(size_t)(c0 + wcc0 + k * 4) * Co + o0 + woo];
                    }
                    if (l > 0) {
#pragma unroll
                        for (int k = 0; k < 4; ++k) {
                            int cc = xcc0 + k * 8;
                            float y = fmaf(rx[k], shsc[c0 + cc], shsh[c0 + cc]);
                            rx[k] = y >= 0.f ? y : 0.2f * y;
                        }
                    }
                    __syncthreads();   // prev-tile compute done before overwrite
#pragma unroll
                    for (int k = 0; k < 4; ++k)
                        Xs[(xcc0 + k * 8) * 32 + xnn] = rx[k];
#pragma unroll
                    for (int k = 0; k < 8; ++k) {
                        Wta[(wcc0 + k * 4) * 68 + woo] = ra[k];
                        Wtb[(wcc0 + k * 4) * 68 + woo] = rb[k];
                    }
                    __syncthreads();
#pragma unroll 8
                    for (int cc = 0; cc < 32; ++cc) {
                        float2 xv = *(const float2*)&Xs[cc * 32 + tn2];
                        float4 wa = *(const float4*)&Wta[cc * 68 + to4];
                        float4 wb = *(const float4*)&Wtb[cc * 68 + to4];
                        float wav[4] = {wa.x, wa.y, wa.z, wa.w};
                        float wbv[4] = {wb.x, wb.y, wb.z, wb.w};
#pragma unroll
                        for (int q = 0; q < 4; ++q) {
                            a2[q].x = fmaf(wav[q], xv.x, a2[q].x);
                            a2[q].y = fmaf(wav[q], xv.y, a2[q].y);
                            b2[q].x = fmaf(wbv[q], xv.x, b2[q].x);
                            b2[q].y = fmaf(wbv[q], xv.y, b2[q].y);
                        }
                    }
                }
                int n = n0 + tn2;
#pragma unroll
                for (int q = 0; q < 4; ++q) {
                    int o = o0 + to4 + q;
                    size_t off = ((size_t)(b * Co + o)) * NPTS + n;
                    cst2(&P.A[off], a2[q]);
                    cst2(&P.Bv[off], b2[q]);
                }
            } else {
                // ---------------- fused gram + top-64 select: block = (i, qo, b)
                int id2 = job - nABx;
                int i  = id2 & 31;
                int qo = (id2 >> 5) & 3;
                int b  = id2 >> 7;
                const float* xb = xin + (size_t)b * bstride;
                float* Xc = smem;                                            // [32][224]
                unsigned long long* Dsh = (unsigned long long*)(smem + 7168); // [8][224]
                float* sqsh = smem + 10752;                                   // [224]
                int q  = t >> 5;          // query in octet (0..7)
                int cl = t & 31;          // candidate lane
                int nq = i * 32 + qo * 8 + q;
                float acc[7];
#pragma unroll
                for (int p = 0; p < 7; ++p) acc[p] = 0.f;
                float sqacc = 0.f;
                for (int c0 = 0; c0 < Cin; c0 += 32) {
                    float r[28]; int rcc[28], rw[28];
#pragma unroll
                    for (int k = 0; k < 28; ++k) {
                        int e = t + k * 256;
                        int cc = e / CAND;
                        int w  = e - cc * CAND;
                        rcc[k] = cc; rw[k] = w;
                        int wb = i - 3 + (w >> 5);
                        wb = wb < 0 ? 0 : (wb > 31 ? 31 : wb);
                        r[k] = xb[(size_t)(c0 + cc) * NPTS + wb * 32 + (w & 31)];   // cached
                    }
                    if (l > 0) {
#pragma unroll
                        for (int k = 0; k < 28; ++k) {
                            float y = fmaf(r[k], shsc[c0 + rcc[k]], shsh[c0 + rcc[k]]);
                            r[k] = y >= 0.f ? y : 0.2f * y;
                        }
                    }
                    __syncthreads();   // prev-chunk reads done before overwrite
#pragma unroll
                    for (int k = 0; k < 28; ++k)
                        Xc[rcc[k] * CAND + rw[k]] = r[k];
                    __syncthreads();
                    // per-column sum of squares (channel-order fmaf chain == old roleA s2v order)
                    if (t < CAND) {
#pragma unroll 8
                        for (int cc = 0; cc < 32; ++cc) {
                            float v = Xc[cc * CAND + t];
                            sqacc = fmaf(v, v, sqacc);
                        }
                    }
                    // gram: per-chunk partial then add (== old Dp-partial + select-sum order)
                    float ch_acc[7];
#pragma unroll
                    for (int p = 0; p < 7; ++p) ch_acc[p] = 0.f;
#pragma unroll 8
                    for (int cc = 0; cc < 32; ++cc) {
                        float qv = Xc[cc * CAND + 96 + qo * 8 + q];
#pragma unroll
                        for (int p = 0; p < 7; ++p)
                            ch_acc[p] = fmaf(qv, Xc[cc * CAND + cl + 32 * p], ch_acc[p]);
                    }
#pragma unroll
                    for (int p = 0; p < 7; ++p) acc[p] += ch_acc[p];
                }
                if (t < CAND) sqsh[t] = sqacc;
                __syncthreads();
                float sqn = sqsh[96 + qo * 8 + q];
                unsigned long long kj[7];
#pragma unroll
                for (int p = 0; p < 7; ++p) {
                    int c = cl + 32 * p;
                    int wb = i - 3 + (c >> 5);
                    bool valid = (wb >= 0) && (wb < 32);
                    float d = 2.f * acc[p] - sqn - sqsh[c];
                    d = valid ? d : NEGV;
                    unsigned u = __float_as_uint(d);
                    u ^= ((unsigned)((int)u >> 31)) | 0x80000000u;
                    unsigned long long key = ((unsigned long long)u << 8) | (unsigned long long)(255 - c);
                    kj[p] = key;
                    Dsh[q * 224 + c] = key;
                }
                __syncthreads();
                int cnt[7] = {0, 0, 0, 0, 0, 0, 0};
                const ulonglong2* row = (const ulonglong2*)(Dsh + q * 224);
#pragma unroll 2
                for (int w2 = 0; w2 < 112; w2 += 4) {
                    ulonglong2 k0 = row[w2], k1 = row[w2 + 1], k2 = row[w2 + 2], k3 = row[w2 + 3];
#pragma unroll
                    for (int p = 0; p < 7; ++p) {
                        unsigned long long kk = kj[p];
                        cnt[p] += (int)(k0.x > kk) + (int)(k0.y > kk) + (int)(k1.x > kk) + (int)(k1.y > kk)
                                + (int)(k2.x > kk) + (int)(k2.y > kk) + (int)(k3.x > kk) + (int)(k3.y > kk);
                    }
                }
#pragma unroll
                for (int p = 0; p < 7; ++p) {
                    int c = cl + 32 * p;
                    if (cnt[p] < KEFF)
                        csti(&idxl[((size_t)b * KEFF + cnt[p]) * NPTS + nq], (i - 3) * 32 + c);   // k-major
                }
            }
            __syncthreads();   // job-end: LDS reuse safe
        }
        gbar(P.bar, ++ep);

        // ================ stage 2: agg (n split into 2 halves -> Co*4 jobs); idx cached ================
        const int CoLg = (Co == 128) ? 7 : 6;
#pragma unroll 1
        for (int job = bid; job < Co * 4; job += NBLK) {
            int o = job & (Co - 1); int rest = job >> CoLg;
            int b = rest & 1; int h = rest >> 1;
            float* Ash = smem;
            float* red = smem + 1024;
            size_t rowoff = (size_t)(b * Co + o) * NPTS;
            {
                float rA[4];
#pragma unroll
                for (int r = 0; r < 4; ++r) rA[r] = cld(&P.A[rowoff + r * 256 + t]);
#pragma unroll
                for (int r = 0; r < 4; ++r) Ash[r * 256 + t] = rA[r];
            }
            __syncthreads();
            float sum = 0.f, sumsq = 0.f;
#pragma unroll 1
            for (int r = 0; r < 2; ++r) {
                int n = h * 512 + r * 256 + t;
                const int* ip = idxl + (size_t)b * KEFF * NPTS + n;
                float s1 = 0.f, s2 = 0.f, mx = -3.4e38f;
#pragma unroll
                for (int kb = 0; kb < 4; ++kb) {
                    int iv[16];
#pragma unroll
                    for (int m = 0; m < 16; ++m)
                        iv[m] = ip[(size_t)(kb * 16 + m) * NPTS];   // cached (versioned, write-once)
                    float av[16];
#pragma unroll
                    for (int m = 0; m < 16; ++m) av[m] = Ash[iv[m]];
#pragma unroll
                    for (int m = 0; m < 16; m += 4) {
                        s1 += av[m] + av[m+1] + av[m+2] + av[m+3];
                        s2 += av[m]*av[m] + av[m+1]*av[m+1] + av[m+2]*av[m+2] + av[m+3]*av[m+3];
                        mx = fmaxf(mx, fmaxf(fmaxf(av[m], av[m+1]), fmaxf(av[m+2], av[m+3])));
                    }
                }
                float bv = cld(&P.Bv[rowoff + n]);
                cst(&P.xconM[((size_t)b * 384 + chOut + o) * NPTS + n], mx + bv);
                sum   += s1 + 64.f * bv;
                sumsq += s2 + 2.f * bv * s1 + 64.f * bv * bv;
            }
            red[t] = sum; __syncthreads();
            for (int s = 128; s > 0; s >>= 1) { if (t < s) red[t] += red[t + s]; __syncthreads(); }
            if (t == 0) cst(&P.part[(size_t)l * 1024 + ((b * Co + o) * 2 + h) * 2 + 0], red[0]);
            __syncthreads();
            red[t] = sumsq; __syncthreads();
            for (int s = 128; s > 0; s >>= 1) { if (t < s) red[t] += red[t + s]; __syncthreads(); }
            if (t == 0) cst(&P.part[(size_t)l * 1024 + ((b * Co + o) * 2 + h) * 2 + 1], red[0]);
            __syncthreads();
        }
        gbar(P.bar, ++ep);
    }

    // ---------------- final GEMM (64o x 32n tiles -> 384 jobs); all reads cached
    for (int ch = t; ch < 384; ch += 256) {
        const float* pl; const float* gl; const float* bl; int o, Col;
        if (ch < 128)      { pl = P.part;         gl = P.g0; bl = P.be0; o = ch;       Col = 128; }
        else if (ch < 256) { pl = P.part + 1024;  gl = P.g1; bl = P.be1; o = ch - 128; Col = 128; }
        else if (ch < 320) { pl = P.part + 2048;  gl = P.g2; bl = P.be2; o = ch - 256; Col = 64;  }
        else               { pl = P.part + 3072;  gl = P.g3; bl = P.be3; o = ch - 320; Col = 64;  }
        float s  = pl[4 * o]     + pl[4 * o + 2]     + pl[4 * (Col + o)]     + pl[4 * (Col + o) + 2];
        float s2 = pl[4 * o + 1] + pl[4 * o + 3]     + pl[4 * (Col + o) + 1] + pl[4 * (Col + o) + 3];
        const float invc = 1.f / 131072.f;
        float mu = s * invc;
        float var = s2 * invc - mu * mu;
        float rs = rsqrtf(var + 1e-5f);
        float sc = gl[o] * rs;
        shsc[ch] = sc;
        shsh[ch] = bl[o] - mu * sc;
    }
    __syncthreads();
    const float* wlT = P.wt + 122880;
#pragma unroll 1
    for (int job = bid; job < 384; job += NBLK) {
        int nt = job & 31; int rest = job >> 5;
        int ot = rest % 6; int b = rest / 6;
        int n0 = nt * 32, o0 = ot * 64;
        int tn2 = (t & 15) * 2, to4 = (t >> 4) * 4;
        int nn = t & 31, cx0 = t >> 5;
        int woo = t & 63, cw0 = t >> 6;
        float* Xs = smem;
        float* Wl = smem + 1024;
        float2 acc2[4];
#pragma unroll
        for (int i = 0; i < 4; ++i) acc2[i] = make_float2(0.f, 0.f);
        for (int c0 = 0; c0 < 384; c0 += 32) {
            float rx[4], rw[8];
#pragma unroll
            for (int k = 0; k < 4; ++k)
                rx[k] = P.xconM[((size_t)b * 384 + c0 + cx0 + k * 8) * NPTS + n0 + nn];   // cached
#pragma unroll
            for (int k = 0; k < 8; ++k)
                rw[k] = wlT[(size_t)(c0 + cw0 + k * 4) * 384 + o0 + woo];
#pragma unroll
            for (int k = 0; k < 4; ++k) {
                int cc = c0 + cx0 + k * 8;
                float y = fmaf(rx[k], shsc[cc], shsh[cc]);
                rx[k] = y >= 0.f ? y : 0.2f * y;
            }
            __syncthreads();
#pragma unroll
            for (int k = 0; k < 4; ++k)
                Xs[(cx0 + k * 8) * 32 + nn] = rx[k];
#pragma unroll
            for (int k = 0; k < 8; ++k)
                Wl[(cw0 + k * 4) * 68 + woo] = rw[k];
            __syncthreads();
#pragma unroll 8
            for (int cc = 0; cc < 32; ++cc) {
                float2 xv = *(const float2*)&Xs[cc * 32 + tn2];
                float4 wv = *(const float4*)&Wl[cc * 68 + to4];
                float wvv[4] = {wv.x, wv.y, wv.z, wv.w};
#pragma unroll
                for (int i = 0; i < 4; ++i) {
                    acc2[i].x = fmaf(wvv[i], xv.x, acc2[i].x);
                    acc2[i].y = fmaf(wvv[i], xv.y, acc2[i].y);
                }
            }
        }
#pragma unroll
        for (int i = 0; i < 4; ++i)
            *(float2*)&P.out[((size_t)b * 384 + o0 + to4 + i) * NPTS + n0 + tn2] = acc2[i];
        __syncthreads();
    }
}

extern "C" void kernel_launch(void* const* d_in, const int* in_sizes, int n_in,
                              void* d_out, int out_size, void* d_ws, size_t ws_size,
                              hipStream_t stream) {
    const float* x  = (const float*)d_in[0];
    const float* w[4]  = {(const float*)d_in[1], (const float*)d_in[4], (const float*)d_in[7], (const float*)d_in[10]};
    const float* g[4]  = {(const float*)d_in[2], (const float*)d_in[5], (const float*)d_in[8], (const float*)d_in[11]};
    const float* be[4] = {(const float*)d_in[3], (const float*)d_in[6], (const float*)d_in[9], (const float*)d_in[12]};
    const float* wl = (const float*)d_in[13];

    float* ws    = (float*)d_ws;
    float* xconM = ws;                       // 786432
    float* A     = xconM + 786432;           // 262144
    float* Bv    = A + 262144;               // 262144
    float* part  = Bv + 262144;              // 4096 (4 layers x 1024, write-once)
    float* wt    = part + 4096;              // 270336
    int*   idx   = (int*)(wt + 270336);      // 4 x 131072 ints (versioned per layer, write-once)
    unsigned* bar = (unsigned*)(idx + 524288);  // (NBLK+1)*BAR_STRIDE uints

    kprep<<<204, 256, 0, stream>>>(w[0], w[1], w[2], w[3], wl, wt, bar);

    MP mp;
    mp.x = x;
    mp.g0 = g[0]; mp.g1 = g[1]; mp.g2 = g[2]; mp.g3 = g[3];
    mp.be0 = be[0]; mp.be1 = be[1]; mp.be2 = be[2]; mp.be3 = be[3];
    mp.xconM = xconM; mp.A = A; mp.Bv = Bv;
    mp.part = part; mp.wt = wt; mp.idx = idx; mp.bar = bar;
    mp.out = (float*)d_out;
    kmega<<<NBLK, 256, 0, stream>>>(mp);
}